// Round 10
// baseline (396.270 us; speedup 1.0000x reference)
//
#include <hip/hip_runtime.h>

// MFVIConstituency: q[b,i,j] = s_con[b,i,j] + sum_k sig(q)[b,j,k] * s_bin[b,i,j,k] * (i!=k)*(j!=k)*mask[b,i,j]
// MAX_ITER=3, output sigmoid(q).
//
// R10: single persistent kernel, homebrew grid barrier (graph-capturable,
// unlike hipLaunchCooperativeKernel which failed capture in R9).
// Block = (batch, j). Its 192 s_bin rows are streamed ONCE (fp32, NT,
// k-mask folded) into a 73.7 KB fp16 LDS slab (R9's register version spilled:
// VGPR=84, 184 MB scratch writes, 547 us). Iter1 is fused into the stream;
// iters 2-3 re-read the LDS slab. Per iteration only sig[b,j,:] (768 B) is
// re-staged. HBM traffic ~= one fp32 read of s_bin (227 MB) + ~5 MB.
//
// Co-residency guarantee for the barrier: grid = 384 blocks; LDS 74.5 KB ->
// exactly 2 blocks/CU; __launch_bounds__(256,2) caps VGPR at 256 -> reg side
// also allows 2 blocks/CU; capacity = 512 >= 384. Barrier uses agent-scope
// atomics (release add = buffer_wbl2, acquire load = buffer_inv) for cross-XCD
// L2 visibility. Phase-cumulative counter, zeroed by hipMemsetAsync per call.

#define S_DIM 192
#define SS (S_DIM * S_DIM)
#define B_DIM 8
#define NROWS (B_DIM * SS)
#define CB 2
#define GRID_B (CB * S_DIM)     // 384 blocks
#define NCHUNK (B_DIM / CB)     // 4
#define NPASS (S_DIM / 16)      // 12: 4 waves x 4 row-groups

typedef float    floatx4 __attribute__((ext_vector_type(4)));
typedef _Float16 halfx4  __attribute__((ext_vector_type(4)));

__device__ __forceinline__ float sigmoidf(float x) {
    return 1.0f / (1.0f + __expf(-x));
}

__device__ __forceinline__ void grid_barrier(unsigned* cnt, unsigned target) {
    __syncthreads();
    if (threadIdx.x == 0) {
        __hip_atomic_fetch_add(cnt, 1u, __ATOMIC_ACQ_REL, __HIP_MEMORY_SCOPE_AGENT);
        while (__hip_atomic_load(cnt, __ATOMIC_RELAXED, __HIP_MEMORY_SCOPE_AGENT) < target)
            __builtin_amdgcn_s_sleep(8);
        (void)__hip_atomic_load(cnt, __ATOMIC_ACQUIRE, __HIP_MEMORY_SCOPE_AGENT);
    }
    __syncthreads();
}

__global__ __launch_bounds__(256, 2)
void fvi_persistent_kernel(const float* __restrict__ s_con,
                           const float* __restrict__ s_bin,
                           const int* __restrict__ mask,
                           float* __restrict__ sigA,
                           float* __restrict__ sigB,
                           float* __restrict__ out,
                           unsigned* __restrict__ barrier_cnt) {
    __shared__ _Float16 st[S_DIM][S_DIM];            // 73728 B, [i][k]
    __shared__ __align__(16) float sig_row[S_DIM];   // 768 B

    const int tid  = threadIdx.x;
    const int wave = tid >> 6;
    const int lane = tid & 63;
    const int grp  = lane >> 4;      // 4 rows per wave-pass
    const int sub  = lane & 15;      // 16 lanes per row
    const int j    = blockIdx.x % S_DIM;
    const int bloc = blockIdx.x / S_DIM;
    unsigned ph = 0;

    for (int chunk = 0; chunk < NCHUNK; ++chunk) {
        const int    b    = chunk * CB + bloc;
        const size_t base = (size_t)b * SS;

        // hoist per-row s_con / mask for the epilogues (only sub==0 lanes use them)
        float sc[NPASS];
        int   mk[NPASS];
        if (sub == 0) {
            #pragma unroll
            for (int p = 0; p < NPASS; ++p) {
                const int i = p * 16 + wave * 4 + grp;
                const size_t row = base + (size_t)i * S_DIM + j;
                sc[p] = s_con[row];
                mk[p] = mask[row];
            }
        }

        // ---- iteration 1, fused with the one-time stream of s_bin into LDS ----
        if (tid < S_DIM) sig_row[tid] = sigmoidf(s_con[base + (size_t)j * S_DIM + tid]);
        __syncthreads();

        #pragma unroll
        for (int p = 0; p < NPASS; ++p) {
            const int i = p * 16 + wave * 4 + grp;
            const floatx4* rowp = reinterpret_cast<const floatx4*>(
                s_bin + (base + (size_t)i * S_DIM + j) * S_DIM);
            float dot = 0.0f;
            #pragma unroll
            for (int c = 0; c < 3; ++c) {
                const int f4 = sub + (c << 4);       // 0..47
                const int k0 = f4 << 2;
                floatx4 sv = __builtin_nontemporal_load(rowp + f4);
                const float m0 = (k0 + 0 != i && k0 + 0 != j) ? sv.x : 0.0f;
                const float m1 = (k0 + 1 != i && k0 + 1 != j) ? sv.y : 0.0f;
                const float m2 = (k0 + 2 != i && k0 + 2 != j) ? sv.z : 0.0f;
                const float m3 = (k0 + 3 != i && k0 + 3 != j) ? sv.w : 0.0f;
                const float4 gv = *reinterpret_cast<const float4*>(&sig_row[k0]);
                dot += m0 * gv.x + m1 * gv.y + m2 * gv.z + m3 * gv.w;
                halfx4 hv;
                hv.x = (_Float16)m0; hv.y = (_Float16)m1;
                hv.z = (_Float16)m2; hv.w = (_Float16)m3;
                *reinterpret_cast<halfx4*>(&st[i][k0]) = hv;
            }
            dot += __shfl_xor(dot, 1, 64);
            dot += __shfl_xor(dot, 2, 64);
            dot += __shfl_xor(dot, 4, 64);
            dot += __shfl_xor(dot, 8, 64);
            if (sub == 0) {
                float q = sc[p] + (mk[p] ? dot : 0.0f);
                sigA[base + (size_t)i * S_DIM + j] = sigmoidf(q);
            }
        }

        ++ph; grid_barrier(barrier_cnt, ph * GRID_B);   // publish sigA

        // ---- iteration 2 (LDS-resident s_bin) ----
        if (tid < S_DIM) sig_row[tid] = sigA[base + (size_t)j * S_DIM + tid];
        __syncthreads();

        #pragma unroll
        for (int p = 0; p < NPASS; ++p) {
            const int i = p * 16 + wave * 4 + grp;
            float dot = 0.0f;
            #pragma unroll
            for (int c = 0; c < 3; ++c) {
                const int f4 = sub + (c << 4);
                const int k0 = f4 << 2;
                halfx4 hv = *reinterpret_cast<const halfx4*>(&st[i][k0]);
                const float4 gv = *reinterpret_cast<const float4*>(&sig_row[k0]);
                dot += (float)hv.x * gv.x + (float)hv.y * gv.y
                     + (float)hv.z * gv.z + (float)hv.w * gv.w;
            }
            dot += __shfl_xor(dot, 1, 64);
            dot += __shfl_xor(dot, 2, 64);
            dot += __shfl_xor(dot, 4, 64);
            dot += __shfl_xor(dot, 8, 64);
            if (sub == 0) {
                float q = sc[p] + (mk[p] ? dot : 0.0f);
                sigB[base + (size_t)i * S_DIM + j] = sigmoidf(q);
            }
        }

        ++ph; grid_barrier(barrier_cnt, ph * GRID_B);   // publish sigB

        // ---- iteration 3 -> out ----
        if (tid < S_DIM) sig_row[tid] = sigB[base + (size_t)j * S_DIM + tid];
        __syncthreads();

        #pragma unroll
        for (int p = 0; p < NPASS; ++p) {
            const int i = p * 16 + wave * 4 + grp;
            float dot = 0.0f;
            #pragma unroll
            for (int c = 0; c < 3; ++c) {
                const int f4 = sub + (c << 4);
                const int k0 = f4 << 2;
                halfx4 hv = *reinterpret_cast<const halfx4*>(&st[i][k0]);
                const float4 gv = *reinterpret_cast<const float4*>(&sig_row[k0]);
                dot += (float)hv.x * gv.x + (float)hv.y * gv.y
                     + (float)hv.z * gv.z + (float)hv.w * gv.w;
            }
            dot += __shfl_xor(dot, 1, 64);
            dot += __shfl_xor(dot, 2, 64);
            dot += __shfl_xor(dot, 4, 64);
            dot += __shfl_xor(dot, 8, 64);
            if (sub == 0) {
                float q = sc[p] + (mk[p] ? dot : 0.0f);
                out[base + (size_t)i * S_DIM + j] = sigmoidf(q);
            }
        }

        __syncthreads();   // protect sig_row / st before next chunk restages
        // chunks use disjoint sigA/sigB/out regions: no inter-chunk grid barrier
    }
}

extern "C" void kernel_launch(void* const* d_in, const int* in_sizes, int n_in,
                              void* d_out, int out_size, void* d_ws, size_t ws_size,
                              hipStream_t stream) {
    const float* s_con = (const float*)d_in[0];
    const float* s_bin = (const float*)d_in[1];
    const int*   mask  = (const int*)d_in[2];   // harness widens bool -> int32
    float*    out  = (float*)d_out;
    float*    sigA = (float*)d_ws;
    float*    sigB = sigA + NROWS;
    unsigned* cnt  = (unsigned*)(sigB + NROWS);

    hipMemsetAsync(cnt, 0, sizeof(unsigned), stream);   // graph-capturable reset
    fvi_persistent_kernel<<<dim3(GRID_B), dim3(256), 0, stream>>>(
        s_con, s_bin, mask, sigA, sigB, out, cnt);
}

// Round 11
// 378.696 us; speedup vs baseline: 1.0464x; 1.0464x over previous
//
#include <hip/hip_runtime.h>

// MFVIConstituency: q[b,i,j] = s_con[b,i,j] + sum_k sig(q)[b,j,k] * s_bin[b,i,j,k] * (i!=k)*(j!=k)*mask[b,i,j]
// MAX_ITER=3, output sigmoid(q).
//
// R11: persistent kernel, block = (b, i)  [R10 used (b,j) and its s_bin access
// pattern -- 768B islands 147KB apart -- collapsed DRAM BW to 0.56 TB/s].
// Block (b,i)'s slab s_bin[b,i,:,:] is 147 KB CONTIGUOUS, streamed once (NT,
// 12-deep batches) into a 73.7 KB fp16 LDS slab st[j][k] with the k-mask
// folded (LDS write addr is linear in load index -> conflict-free).
// Each iteration: for output (b,i,j), dot st[j][:] against sig[b,j,:] --
// the sig matrix (0.59 MB fp16/batch) is shared by all 192 blocks of the
// batch -> L2-served. sig0 = sigmoid(s_con) precomputed fp16 by a pre-kernel.
// Grid barrier (proven in R10: agent-scope acq_rel add + acquire) between
// iterations; 4 chunks x 2 batches, 384 blocks, guaranteed 2 blocks/CU by LDS.
// HBM traffic ~= one fp32 read of s_bin (227 MB) + ~4 MB.

#define S_DIM 192
#define SS (S_DIM * S_DIM)
#define B_DIM 8
#define NROWS (B_DIM * SS)
#define CB 2
#define GRID_B (CB * S_DIM)        // 384 blocks
#define NCHUNK (B_DIM / CB)        // 4
#define NPASS (S_DIM / 16)         // 12: 4 waves x 4 j's
#define F4_PER_THREAD (SS / 4 / 256)  // 36
#define SBATCH 12

typedef float    floatx4 __attribute__((ext_vector_type(4)));
typedef _Float16 halfx4  __attribute__((ext_vector_type(4)));

__device__ __forceinline__ float sigmoidf(float x) {
    return 1.0f / (1.0f + __expf(-x));
}

__device__ __forceinline__ void grid_barrier(unsigned* cnt, unsigned target) {
    __syncthreads();
    if (threadIdx.x == 0) {
        __hip_atomic_fetch_add(cnt, 1u, __ATOMIC_ACQ_REL, __HIP_MEMORY_SCOPE_AGENT);
        while (__hip_atomic_load(cnt, __ATOMIC_RELAXED, __HIP_MEMORY_SCOPE_AGENT) < target)
            __builtin_amdgcn_s_sleep(8);
        (void)__hip_atomic_load(cnt, __ATOMIC_ACQUIRE, __HIP_MEMORY_SCOPE_AGENT);
    }
    __syncthreads();
}

// sig0 = sigmoid(s_con) as fp16 (4 elements/thread)
__global__ __launch_bounds__(256) void sig0_kernel(const float* __restrict__ s_con,
                                                   _Float16* __restrict__ sig0) {
    const int idx = (blockIdx.x * 256 + threadIdx.x) * 4;
    floatx4 v = *reinterpret_cast<const floatx4*>(s_con + idx);
    halfx4 h;
    h.x = (_Float16)sigmoidf(v.x);
    h.y = (_Float16)sigmoidf(v.y);
    h.z = (_Float16)sigmoidf(v.z);
    h.w = (_Float16)sigmoidf(v.w);
    *reinterpret_cast<halfx4*>(sig0 + idx) = h;
}

template <bool LAST>
__device__ __forceinline__ void fvi_iter(const _Float16* __restrict__ sig_src,  // + b*SS
                                         const float* __restrict__ s_con_m,     // + b*SS
                                         const int* __restrict__ mask_m,        // + b*SS
                                         _Float16* __restrict__ o16,            // + b*SS
                                         float* __restrict__ o32,               // + b*SS
                                         const _Float16 (*st)[S_DIM],
                                         int i, int wave, int grp, int sub) {
    #pragma unroll
    for (int p = 0; p < NPASS; ++p) {
        const int j = p * 16 + wave * 4 + grp;
        float dot = 0.0f;
        #pragma unroll
        for (int c = 0; c < 3; ++c) {
            const int k0 = (sub + (c << 4)) << 2;
            halfx4 sb = *reinterpret_cast<const halfx4*>(&st[j][k0]);
            halfx4 sg = *reinterpret_cast<const halfx4*>(sig_src + (size_t)j * S_DIM + k0);
            dot += (float)sb.x * (float)sg.x + (float)sb.y * (float)sg.y
                 + (float)sb.z * (float)sg.z + (float)sb.w * (float)sg.w;
        }
        dot += __shfl_xor(dot, 1, 64);
        dot += __shfl_xor(dot, 2, 64);
        dot += __shfl_xor(dot, 4, 64);
        dot += __shfl_xor(dot, 8, 64);
        if (sub == 0) {
            const int idx = i * S_DIM + j;
            float q = s_con_m[idx] + (mask_m[idx] ? dot : 0.0f);
            float s = sigmoidf(q);
            if (LAST) o32[idx] = s; else o16[idx] = (_Float16)s;
        }
    }
}

__global__ __launch_bounds__(256, 2)
void fvi_persistent_kernel(const float* __restrict__ s_con,
                           const float* __restrict__ s_bin,
                           const int* __restrict__ mask,
                           const _Float16* __restrict__ sig0,
                           _Float16* __restrict__ sigA,
                           _Float16* __restrict__ sigB,
                           float* __restrict__ out,
                           unsigned* __restrict__ barrier_cnt) {
    __shared__ _Float16 st[S_DIM][S_DIM];   // 73728 B -> 2 blocks/CU guaranteed

    const int tid  = threadIdx.x;
    const int wave = tid >> 6;
    const int lane = tid & 63;
    const int grp  = lane >> 4;
    const int sub  = lane & 15;
    const int i    = blockIdx.x % S_DIM;    // consecutive blocks -> consecutive slabs
    const int bloc = blockIdx.x / S_DIM;
    unsigned ph = 0;

    for (int chunk = 0; chunk < NCHUNK; ++chunk) {
        const int    b     = chunk * CB + bloc;
        const size_t mbase = (size_t)b * SS;
        const size_t slab  = (mbase + (size_t)i * S_DIM) * S_DIM;

        // ---- stream contiguous 147 KB slab -> fp16 LDS, k-mask folded ----
        {
            const floatx4* src = reinterpret_cast<const floatx4*>(s_bin + slab);
            _Float16* stf = &st[0][0];
            #pragma unroll
            for (int bb = 0; bb < F4_PER_THREAD / SBATCH; ++bb) {
                floatx4 r[SBATCH];
                #pragma unroll
                for (int u = 0; u < SBATCH; ++u)
                    r[u] = __builtin_nontemporal_load(src + ((bb * SBATCH + u) * 256 + tid));
                #pragma unroll
                for (int u = 0; u < SBATCH; ++u) {
                    const int f  = (bb * SBATCH + u) * 256 + tid;
                    const int j  = f / (S_DIM / 4);
                    const int k0 = (f % (S_DIM / 4)) * 4;
                    halfx4 h;
                    h.x = (_Float16)((k0 + 0 != i && k0 + 0 != j) ? r[u].x : 0.0f);
                    h.y = (_Float16)((k0 + 1 != i && k0 + 1 != j) ? r[u].y : 0.0f);
                    h.z = (_Float16)((k0 + 2 != i && k0 + 2 != j) ? r[u].z : 0.0f);
                    h.w = (_Float16)((k0 + 3 != i && k0 + 3 != j) ? r[u].w : 0.0f);
                    *reinterpret_cast<halfx4*>(stf + (size_t)f * 4) = h;   // linear addr: conflict-free
                }
            }
        }
        __syncthreads();

        fvi_iter<false>(sig0 + mbase, s_con + mbase, mask + mbase,
                        sigA + mbase, nullptr, st, i, wave, grp, sub);
        ++ph; grid_barrier(barrier_cnt, ph * GRID_B);     // publish sigA

        fvi_iter<false>(sigA + mbase, s_con + mbase, mask + mbase,
                        sigB + mbase, nullptr, st, i, wave, grp, sub);
        ++ph; grid_barrier(barrier_cnt, ph * GRID_B);     // publish sigB

        fvi_iter<true>(sigB + mbase, s_con + mbase, mask + mbase,
                       nullptr, out + mbase, st, i, wave, grp, sub);

        __syncthreads();   // st reused by next chunk's stream
        // chunks touch disjoint b-regions: no inter-chunk grid barrier needed
    }
}

extern "C" void kernel_launch(void* const* d_in, const int* in_sizes, int n_in,
                              void* d_out, int out_size, void* d_ws, size_t ws_size,
                              hipStream_t stream) {
    const float* s_con = (const float*)d_in[0];
    const float* s_bin = (const float*)d_in[1];
    const int*   mask  = (const int*)d_in[2];   // harness widens bool -> int32
    float* out = (float*)d_out;

    _Float16* sig0 = (_Float16*)d_ws;
    _Float16* sigA = sig0 + NROWS;
    _Float16* sigB = sigA + NROWS;
    unsigned* cnt  = (unsigned*)(sigB + NROWS);

    sig0_kernel<<<NROWS / 1024, 256, 0, stream>>>(s_con, sig0);
    hipMemsetAsync(cnt, 0, sizeof(unsigned), stream);
    fvi_persistent_kernel<<<dim3(GRID_B), dim3(256), 0, stream>>>(
        s_con, s_bin, mask, sig0, sigA, sigB, out, cnt);
}

// Round 12
// 270.559 us; speedup vs baseline: 1.4646x; 1.3997x over previous
//
#include <hip/hip_runtime.h>

// MFVIConstituency: q[b,i,j] = s_con[b,i,j] + sum_k sig(q)[b,j,k] * s_bin[b,i,j,k] * (i!=k)*(j!=k)*mask[b,i,j]
// MAX_ITER=3, output sigmoid(q).
//
// R12: persistent kernel, block = i (192 blocks x 512 thr, 1 block/CU exact).
// Per batch b the block streams its contiguous 147 KB slab s_bin[b,i,:,:] ONCE
// into an fp16 LDS slab (k-mask folded), double-buffered so batch b+1's stream
// is software-pipelined under batch b's compute/barrier waits.
// Grid barrier rebuilt RMW-free: per-block release word (64B stride) + master
// scan (block 0 wave 0, distributed lines) + 8-line epoch broadcast + acquire
// fences. R10/R11's single-line RMW spin + 384-on-256 imbalance suspected for
// their ~300 us of idle.

#define S_DIM 192
#define SS (S_DIM * S_DIM)
#define B_DIM 8
#define NROWS (B_DIM * SS)
#define NTHREADS 512
#define GRID_B S_DIM                 // 192 blocks
#define NPASS (S_DIM / 32)           // 6 passes: 8 waves x 4 rows
#define SB 6                         // stream sub-batch (3 x 6 float4/thread)
#define AWS 16                       // arrive/epoch stride in words (64 B)

typedef float    floatx4 __attribute__((ext_vector_type(4)));
typedef _Float16 halfx4  __attribute__((ext_vector_type(4)));

__device__ __forceinline__ float sigmoidf(float x) {
    return 1.0f / (1.0f + __expf(-x));
}

// ---- low-contention grid barrier (192 co-resident blocks, no RMWs) ----
__device__ __forceinline__ void bar_arrive(unsigned* arr, int bid, unsigned ph) {
    __syncthreads();   // drains all threads' global stores (vmcnt0 before barrier)
    if (threadIdx.x == 0) {
        __builtin_amdgcn_fence(__ATOMIC_RELEASE, "agent");
        __hip_atomic_store(&arr[bid * AWS], ph, __ATOMIC_RELAXED, __HIP_MEMORY_SCOPE_AGENT);
    }
}

__device__ __forceinline__ void bar_wait(unsigned* arr, unsigned* ep, int bid, unsigned ph) {
    if (bid == 0 && threadIdx.x < 64) {
        const int l = threadIdx.x;
        for (;;) {
            bool ok = true;
            #pragma unroll
            for (int t = 0; t < 3; ++t)
                ok &= (__hip_atomic_load(&arr[(l + t * 64) * AWS], __ATOMIC_RELAXED,
                                         __HIP_MEMORY_SCOPE_AGENT) >= ph);
            if (__all(ok)) break;
            __builtin_amdgcn_s_sleep(4);
        }
        __builtin_amdgcn_fence(__ATOMIC_ACQUIRE, "agent");
        if (l < 8)
            __hip_atomic_store(&ep[l * AWS], ph, __ATOMIC_RELAXED, __HIP_MEMORY_SCOPE_AGENT);
    }
    if (threadIdx.x == 0) {
        while (__hip_atomic_load(&ep[(bid & 7) * AWS], __ATOMIC_RELAXED,
                                 __HIP_MEMORY_SCOPE_AGENT) < ph)
            __builtin_amdgcn_s_sleep(16);
        __builtin_amdgcn_fence(__ATOMIC_ACQUIRE, "agent");
    }
    __syncthreads();
}

// sig0 = sigmoid(s_con) as fp16
__global__ __launch_bounds__(256) void sig0_kernel(const float* __restrict__ s_con,
                                                   _Float16* __restrict__ sig0) {
    const int idx = (blockIdx.x * 256 + threadIdx.x) * 4;
    floatx4 v = *reinterpret_cast<const floatx4*>(s_con + idx);
    halfx4 h;
    h.x = (_Float16)sigmoidf(v.x);
    h.y = (_Float16)sigmoidf(v.y);
    h.z = (_Float16)sigmoidf(v.z);
    h.w = (_Float16)sigmoidf(v.w);
    *reinterpret_cast<halfx4*>(sig0 + idx) = h;
}

// ---- stream helpers: 6 float4 loads to regs / masked fp16 LDS stores ----
__device__ __forceinline__ void issue_sb(const floatx4* __restrict__ src, int bb,
                                         floatx4 r[SB], int tid) {
    #pragma unroll
    for (int u = 0; u < SB; ++u)
        r[u] = src[(bb * SB + u) * NTHREADS + tid];
}

__device__ __forceinline__ void store_sb(_Float16* __restrict__ slab, int bb,
                                         const floatx4 r[SB], int tid, int i) {
    #pragma unroll
    for (int u = 0; u < SB; ++u) {
        const int f  = (bb * SB + u) * NTHREADS + tid;
        const int j  = f / (S_DIM / 4);
        const int k0 = (f % (S_DIM / 4)) * 4;
        halfx4 h;
        h.x = (_Float16)((k0 + 0 != i && k0 + 0 != j) ? r[u].x : 0.0f);
        h.y = (_Float16)((k0 + 1 != i && k0 + 1 != j) ? r[u].y : 0.0f);
        h.z = (_Float16)((k0 + 2 != i && k0 + 2 != j) ? r[u].z : 0.0f);
        h.w = (_Float16)((k0 + 3 != i && k0 + 3 != j) ? r[u].w : 0.0f);
        *reinterpret_cast<halfx4*>(slab + (size_t)f * 4) = h;   // linear: conflict-free
    }
}

template <bool LAST>
__device__ __forceinline__ void fvi_iter(const _Float16* __restrict__ sig,     // + b*SS
                                         const float* __restrict__ s_con_b,
                                         const int* __restrict__ mask_b,
                                         _Float16* __restrict__ o16,
                                         float* __restrict__ o32,
                                         const _Float16* __restrict__ slab,
                                         int i, int wave, int grp, int sub) {
    #pragma unroll
    for (int p = 0; p < NPASS; ++p) {
        const int j = p * 32 + wave * 4 + grp;
        float dot = 0.0f;
        #pragma unroll
        for (int c = 0; c < 3; ++c) {
            const int k0 = (sub + (c << 4)) << 2;
            halfx4 sb = *reinterpret_cast<const halfx4*>(slab + j * S_DIM + k0);
            halfx4 sg = *reinterpret_cast<const halfx4*>(sig + (size_t)j * S_DIM + k0);
            dot += (float)sb.x * (float)sg.x + (float)sb.y * (float)sg.y
                 + (float)sb.z * (float)sg.z + (float)sb.w * (float)sg.w;
        }
        dot += __shfl_xor(dot, 1, 64);
        dot += __shfl_xor(dot, 2, 64);
        dot += __shfl_xor(dot, 4, 64);
        dot += __shfl_xor(dot, 8, 64);
        if (sub == 0) {
            const int idx = i * S_DIM + j;
            float q = s_con_b[idx] + (mask_b[idx] ? dot : 0.0f);
            float s = sigmoidf(q);
            if (LAST) o32[idx] = s; else o16[idx] = (_Float16)s;
        }
    }
}

__global__ __launch_bounds__(NTHREADS, 1)
void fvi_persistent_kernel(const float* __restrict__ s_con,
                           const float* __restrict__ s_bin,
                           const int* __restrict__ mask,
                           const _Float16* __restrict__ sig0,
                           _Float16* __restrict__ sigA,
                           _Float16* __restrict__ sigB,
                           float* __restrict__ out,
                           unsigned* __restrict__ arr,
                           unsigned* __restrict__ ep) {
    __shared__ _Float16 slab[2][SS];   // 2 x 73728 B -> 1 block/CU guaranteed

    const int tid  = threadIdx.x;
    const int wave = tid >> 6;
    const int lane = tid & 63;
    const int grp  = lane >> 4;
    const int sub  = lane & 15;
    const int i    = blockIdx.x;
    const int bid  = blockIdx.x;
    unsigned ph = 0;

    // prologue: stream batch 0's slab
    {
        const floatx4* src = reinterpret_cast<const floatx4*>(s_bin + ((size_t)i * S_DIM) * S_DIM);
        floatx4 r[SB];
        #pragma unroll
        for (int bb = 0; bb < 3; ++bb) { issue_sb(src, bb, r, tid); store_sb(slab[0], bb, r, tid, i); }
    }
    __syncthreads();

    for (int b = 0; b < B_DIM; ++b) {
        const int cur = b & 1;
        _Float16* scur = slab[cur];
        _Float16* snxt = slab[cur ^ 1];
        const size_t mb = (size_t)b * SS;
        const floatx4* nsrc = reinterpret_cast<const floatx4*>(
            s_bin + ((size_t)(b + 1) * SS + (size_t)i * S_DIM) * S_DIM);   // deref only if b<7
        const bool pf = (b < B_DIM - 1);

        floatx4 r0[SB], r1[SB], r2[SB];

        if (pf) issue_sb(nsrc, 0, r0, tid);
        fvi_iter<false>(sig0 + mb, s_con + mb, mask + mb, sigA + mb, nullptr, scur, i, wave, grp, sub);
        ++ph; bar_arrive(arr, bid, ph);
        if (pf) { store_sb(snxt, 0, r0, tid, i); issue_sb(nsrc, 1, r1, tid); }
        bar_wait(arr, ep, bid, ph);

        fvi_iter<false>(sigA + mb, s_con + mb, mask + mb, sigB + mb, nullptr, scur, i, wave, grp, sub);
        ++ph; bar_arrive(arr, bid, ph);
        if (pf) { store_sb(snxt, 1, r1, tid, i); issue_sb(nsrc, 2, r2, tid); }
        bar_wait(arr, ep, bid, ph);

        fvi_iter<true>(sigB + mb, s_con + mb, mask + mb, nullptr, out + mb, scur, i, wave, grp, sub);
        if (pf) store_sb(snxt, 2, r2, tid, i);
        __syncthreads();   // slab handoff: all reads of scur & writes of snxt done
    }
}

extern "C" void kernel_launch(void* const* d_in, const int* in_sizes, int n_in,
                              void* d_out, int out_size, void* d_ws, size_t ws_size,
                              hipStream_t stream) {
    const float* s_con = (const float*)d_in[0];
    const float* s_bin = (const float*)d_in[1];
    const int*   mask  = (const int*)d_in[2];   // harness widens bool -> int32
    float* out = (float*)d_out;

    _Float16* sig0 = (_Float16*)d_ws;
    _Float16* sigA = sig0 + NROWS;
    _Float16* sigB = sigA + NROWS;
    unsigned* arr  = (unsigned*)(sigB + NROWS);       // 192 x 64B arrive words
    unsigned* ep   = arr + GRID_B * AWS;              // 8 x 64B epoch words

    sig0_kernel<<<NROWS / 1024, 256, 0, stream>>>(s_con, sig0);
    hipMemsetAsync(arr, 0, (GRID_B + 8) * AWS * sizeof(unsigned), stream);
    fvi_persistent_kernel<<<dim3(GRID_B), dim3(NTHREADS), 0, stream>>>(
        s_con, s_bin, mask, sig0, sigA, sigB, out, arr, ep);
}

// Round 13
// 118.712 us; speedup vs baseline: 3.3381x; 2.2791x over previous
//
#include <hip/hip_runtime.h>

// MFVIConstituency: q[b,i,j] = s_con[b,i,j] + sum_k sig(q)[b,j,k] * s_bin[b,i,j,k] * (i!=k)*(j!=k)*mask[b,i,j]
// MAX_ITER=3, output sigmoid(q). Memory-bound.
//
// R13: back to the proven R6 3-dispatch structure (persistent/grid-barrier
// designs R9-R12 all lose: cross-XCD barriers cost ~10us each vs ~3us dispatch
// boundaries, and L3 residency gives no rate benefit on this part).
// Byte floor: 227 MB fp32 s_bin read + 113 MB fp16 masked copy write (K1),
// then 113 MB fp16 read x2 (K2,K3) = 566 MB. New in R13: the copy is written
// and read NON-TEMPORALLY (write-combine, no L2 allocate; read-once) to push
// the mixed-stream rate toward the 7.2 TB/s fill ceiling.
//
// Layout: one wave = 4 consecutive (b,i,j) rows; 16 lanes per row; 3 float4
// per lane -> all 64 lanes stream, fully-used contiguous segments.

#define S_DIM 192
#define SS (S_DIM * S_DIM)
#define B_DIM 8
#define NROWS (B_DIM * SS)   // 294912 outputs

typedef float    floatx4 __attribute__((ext_vector_type(4)));
typedef _Float16 halfx4  __attribute__((ext_vector_type(4)));

__device__ __forceinline__ float sigmoidf(float x) {
    return 1.0f / (1.0f + __expf(-x));
}

// K1: fp32 s_bin (NT stream), fold k-mask, emit fp16 copy (NT store) + sig(q1)
__global__ __launch_bounds__(256) void fvi_first_kernel(const float* __restrict__ s_con,
                                                        const float* __restrict__ s_bin,
                                                        const int* __restrict__ mask,
                                                        halfx4* __restrict__ sbh,
                                                        float* __restrict__ sig_out) {
    const int wave = threadIdx.x >> 6;
    const int lane = threadIdx.x & 63;
    const int grp  = lane >> 4;
    const int sub  = lane & 15;
    const int row  = (blockIdx.x * 4 + wave) * 4 + grp;

    const int b   = row / SS;
    const int rem = row - b * SS;
    const int i   = rem / S_DIM;
    const int j   = rem - i * S_DIM;

    const floatx4* __restrict__ srow = reinterpret_cast<const floatx4*>(s_bin + (size_t)row * S_DIM);
    const float4*  __restrict__ grow = reinterpret_cast<const float4*>(s_con + (size_t)(b * SS + j * S_DIM));
    halfx4* __restrict__ hrow = sbh + (size_t)row * (S_DIM / 4);

    float dot = 0.0f;
    #pragma unroll
    for (int c = 0; c < 3; ++c) {
        const int f4 = sub + (c << 4);               // 0..47
        floatx4 sv = __builtin_nontemporal_load(srow + f4);
        float4  gv = grow[f4];
        const int k0 = f4 << 2;
        const float m0 = (k0 + 0 != i && k0 + 0 != j) ? sv.x : 0.0f;
        const float m1 = (k0 + 1 != i && k0 + 1 != j) ? sv.y : 0.0f;
        const float m2 = (k0 + 2 != i && k0 + 2 != j) ? sv.z : 0.0f;
        const float m3 = (k0 + 3 != i && k0 + 3 != j) ? sv.w : 0.0f;
        dot += m0 * sigmoidf(gv.x) + m1 * sigmoidf(gv.y)
             + m2 * sigmoidf(gv.z) + m3 * sigmoidf(gv.w);
        halfx4 hv;
        hv.x = (_Float16)m0; hv.y = (_Float16)m1;
        hv.z = (_Float16)m2; hv.w = (_Float16)m3;
        __builtin_nontemporal_store(hv, hrow + f4);
    }

    dot += __shfl_xor(dot, 1, 64);
    dot += __shfl_xor(dot, 2, 64);
    dot += __shfl_xor(dot, 4, 64);
    dot += __shfl_xor(dot, 8, 64);

    if (sub == 0) {
        float q = s_con[row] + (mask[row] ? dot : 0.0f);
        sig_out[row] = sigmoidf(q);
    }
}

// K2/K3: NT-read masked fp16 copy (read-once), no k-mask needed
__global__ __launch_bounds__(256) void fvi_iter_kernel(const float* __restrict__ s_con,
                                                       const halfx4* __restrict__ sbh,
                                                       const int* __restrict__ mask,
                                                       const float* __restrict__ sig_in,
                                                       float* __restrict__ sig_out) {
    const int wave = threadIdx.x >> 6;
    const int lane = threadIdx.x & 63;
    const int grp  = lane >> 4;
    const int sub  = lane & 15;
    const int row  = (blockIdx.x * 4 + wave) * 4 + grp;

    const int b   = row / SS;
    const int rem = row - b * SS;
    const int j   = rem - (rem / S_DIM) * S_DIM;

    const halfx4* __restrict__ hrow = sbh + (size_t)row * (S_DIM / 4);
    const float4* __restrict__ grow = reinterpret_cast<const float4*>(sig_in + (size_t)(b * SS + j * S_DIM));

    float dot = 0.0f;
    #pragma unroll
    for (int c = 0; c < 3; ++c) {
        const int f4 = sub + (c << 4);
        halfx4 hv = __builtin_nontemporal_load(hrow + f4);
        float4 gv = grow[f4];
        dot += (float)hv.x * gv.x + (float)hv.y * gv.y
             + (float)hv.z * gv.z + (float)hv.w * gv.w;
    }

    dot += __shfl_xor(dot, 1, 64);
    dot += __shfl_xor(dot, 2, 64);
    dot += __shfl_xor(dot, 4, 64);
    dot += __shfl_xor(dot, 8, 64);

    if (sub == 0) {
        float q = s_con[row] + (mask[row] ? dot : 0.0f);
        sig_out[row] = sigmoidf(q);
    }
}

extern "C" void kernel_launch(void* const* d_in, const int* in_sizes, int n_in,
                              void* d_out, int out_size, void* d_ws, size_t ws_size,
                              hipStream_t stream) {
    const float* s_con = (const float*)d_in[0];
    const float* s_bin = (const float*)d_in[1];
    const int*   mask  = (const int*)d_in[2];   // harness widens bool -> int32
    float* out  = (float*)d_out;
    float* sigA = (float*)d_ws;
    float* sigB = sigA + NROWS;
    halfx4* sbh = reinterpret_cast<halfx4*>(sigB + NROWS);  // 113 MB fp16 masked copy

    const dim3 grid(NROWS / 16);                // 16 rows per 256-thread block

    fvi_first_kernel<<<grid, 256, 0, stream>>>(s_con, s_bin, mask, sbh, sigA);
    fvi_iter_kernel <<<grid, 256, 0, stream>>>(s_con, sbh, mask, sigA, sigB);
    fvi_iter_kernel <<<grid, 256, 0, stream>>>(s_con, sbh, mask, sigB, out);
}

// Round 14
// 100.033 us; speedup vs baseline: 3.9614x; 1.1867x over previous
//
#include <hip/hip_runtime.h>

// MFVIConstituency: q[b,i,j] = s_con[b,i,j] + sum_k sig(q)[b,j,k] * s_bin[b,i,j,k] * (i!=k)*(j!=k)*mask[b,i,j]
// MAX_ITER=3, output sigmoid(q). Memory-bound; byte floor 566 MB
// (227 fp32 s_bin read + 113 fp16 masked-copy write + 2x113 read).
//
// R14 = R6 structure (persistent/grid-barrier designs R9-R12 all lose; NT on
// the copy hurts, R13) + rate micro-fixes:
//  - sig kept fp16 end-to-end (sigh0 precomputed; halves sig streams, removes
//    sigmoid chain from K1's inner loop)
//  - K1 stores widened to 16B via lane-pair shuffle (write-combining)
//  - K2/K3: 8 lanes/row, all 16B loads (halfx8 sbh + halfx8 sigh)
// NT only on the one-shot fp32 s_bin read (proven R6 config).

#define S_DIM 192
#define SS (S_DIM * S_DIM)
#define B_DIM 8
#define NROWS (B_DIM * SS)   // 294912 outputs

typedef float    floatx4 __attribute__((ext_vector_type(4)));
typedef _Float16 halfx4  __attribute__((ext_vector_type(4)));
typedef _Float16 halfx8  __attribute__((ext_vector_type(8)));

__device__ __forceinline__ float sigmoidf(float x) {
    return 1.0f / (1.0f + __expf(-x));
}

// pre: sigh0 = sigmoid(s_con) as fp16, 4 elems/thread
__global__ __launch_bounds__(256) void sig0_kernel(const float* __restrict__ s_con,
                                                   _Float16* __restrict__ sigh0) {
    const int idx = (blockIdx.x * 256 + threadIdx.x) * 4;
    floatx4 v = *reinterpret_cast<const floatx4*>(s_con + idx);
    halfx4 h;
    h.x = (_Float16)sigmoidf(v.x);
    h.y = (_Float16)sigmoidf(v.y);
    h.z = (_Float16)sigmoidf(v.z);
    h.w = (_Float16)sigmoidf(v.w);
    *reinterpret_cast<halfx4*>(sigh0 + idx) = h;
}

// K1: fp32 s_bin (NT) -> masked fp16 copy (16B paired stores) + iter1 -> sighA
__global__ __launch_bounds__(256) void fvi_first_kernel(const float* __restrict__ s_con,
                                                        const float* __restrict__ s_bin,
                                                        const int* __restrict__ mask,
                                                        const _Float16* __restrict__ sigh0,
                                                        halfx8* __restrict__ sbh8,
                                                        _Float16* __restrict__ sigh_out) {
    const int wave = threadIdx.x >> 6;
    const int lane = threadIdx.x & 63;
    const int grp  = lane >> 4;                      // 4 rows per wave
    const int sub  = lane & 15;                      // 16 lanes per row
    const int row  = (blockIdx.x * 4 + wave) * 4 + grp;

    const int b   = row / SS;
    const int rem = row - b * SS;
    const int i   = rem / S_DIM;
    const int j   = rem - i * S_DIM;

    const floatx4* __restrict__ srow = reinterpret_cast<const floatx4*>(s_bin + (size_t)row * S_DIM);
    const halfx4*  __restrict__ grow = reinterpret_cast<const halfx4*>(sigh0 + (size_t)(b * SS + j * S_DIM));
    halfx8* __restrict__ hrow = sbh8 + (size_t)row * (S_DIM / 8);

    float dot = 0.0f;
    #pragma unroll
    for (int c = 0; c < 3; ++c) {
        const int f4 = sub + (c << 4);               // 0..47
        floatx4 sv = __builtin_nontemporal_load(srow + f4);
        halfx4  gv = grow[f4];
        const int k0 = f4 << 2;
        const float m0 = (k0 + 0 != i && k0 + 0 != j) ? sv.x : 0.0f;
        const float m1 = (k0 + 1 != i && k0 + 1 != j) ? sv.y : 0.0f;
        const float m2 = (k0 + 2 != i && k0 + 2 != j) ? sv.z : 0.0f;
        const float m3 = (k0 + 3 != i && k0 + 3 != j) ? sv.w : 0.0f;
        dot += m0 * (float)gv.x + m1 * (float)gv.y + m2 * (float)gv.z + m3 * (float)gv.w;
        halfx4 hv;
        hv.x = (_Float16)m0; hv.y = (_Float16)m1;
        hv.z = (_Float16)m2; hv.w = (_Float16)m3;
        // pair lanes: even lane stores 16B (own 8B + partner's 8B)
        int2 hb = __builtin_bit_cast(int2, hv);
        int px = __shfl_down(hb.x, 1, 64);
        int py = __shfl_down(hb.y, 1, 64);
        if (!(sub & 1)) {
            int4 w4 = { hb.x, hb.y, px, py };
            hrow[f4 >> 1] = __builtin_bit_cast(halfx8, w4);
        }
    }

    dot += __shfl_xor(dot, 1, 64);
    dot += __shfl_xor(dot, 2, 64);
    dot += __shfl_xor(dot, 4, 64);
    dot += __shfl_xor(dot, 8, 64);

    if (sub == 0) {
        float q = s_con[row] + (mask[row] ? dot : 0.0f);
        sigh_out[row] = (_Float16)sigmoidf(q);
    }
}

// K2/K3: 8 lanes/row, 3x halfx8 sbh + 3x halfx8 sigh (all 16B loads)
template <bool LAST>
__global__ __launch_bounds__(256) void fvi_iter_kernel(const float* __restrict__ s_con,
                                                       const halfx8* __restrict__ sbh8,
                                                       const int* __restrict__ mask,
                                                       const _Float16* __restrict__ sigh_in,
                                                       _Float16* __restrict__ sigh_out,
                                                       float* __restrict__ out32) {
    const int wave = threadIdx.x >> 6;
    const int lane = threadIdx.x & 63;
    const int grp  = lane >> 3;                      // 8 rows per wave
    const int sub  = lane & 7;                       // 8 lanes per row
    const int row  = (blockIdx.x * 4 + wave) * 8 + grp;

    const int b   = row / SS;
    const int rem = row - b * SS;
    const int j   = rem - (rem / S_DIM) * S_DIM;

    const halfx8* __restrict__ hrow = sbh8 + (size_t)row * (S_DIM / 8);
    const halfx8* __restrict__ grow = reinterpret_cast<const halfx8*>(sigh_in + (size_t)(b * SS + j * S_DIM));

    float dot = 0.0f;
    #pragma unroll
    for (int c = 0; c < 3; ++c) {
        const int f8 = sub + (c << 3);               // 0..23
        halfx8 h = hrow[f8];
        halfx8 g = grow[f8];
        dot += (float)h[0] * (float)g[0] + (float)h[1] * (float)g[1]
             + (float)h[2] * (float)g[2] + (float)h[3] * (float)g[3]
             + (float)h[4] * (float)g[4] + (float)h[5] * (float)g[5]
             + (float)h[6] * (float)g[6] + (float)h[7] * (float)g[7];
    }

    dot += __shfl_xor(dot, 1, 64);
    dot += __shfl_xor(dot, 2, 64);
    dot += __shfl_xor(dot, 4, 64);

    if (sub == 0) {
        float q = s_con[row] + (mask[row] ? dot : 0.0f);
        float s = sigmoidf(q);
        if (LAST) out32[row] = s; else sigh_out[row] = (_Float16)s;
    }
}

extern "C" void kernel_launch(void* const* d_in, const int* in_sizes, int n_in,
                              void* d_out, int out_size, void* d_ws, size_t ws_size,
                              hipStream_t stream) {
    const float* s_con = (const float*)d_in[0];
    const float* s_bin = (const float*)d_in[1];
    const int*   mask  = (const int*)d_in[2];   // harness widens bool -> int32
    float* out = (float*)d_out;

    _Float16* sigh0 = (_Float16*)d_ws;
    _Float16* sighA = sigh0 + NROWS;
    _Float16* sighB = sighA + NROWS;
    halfx8*   sbh8  = reinterpret_cast<halfx8*>(sighB + NROWS);  // 113 MB fp16 masked copy

    sig0_kernel<<<NROWS / 1024, 256, 0, stream>>>(s_con, sigh0);
    fvi_first_kernel<<<NROWS / 16, 256, 0, stream>>>(s_con, s_bin, mask, sigh0, sbh8, sighA);
    fvi_iter_kernel<false><<<NROWS / 32, 256, 0, stream>>>(s_con, sbh8, mask, sighA, sighB, nullptr);
    fvi_iter_kernel<true ><<<NROWS / 32, 256, 0, stream>>>(s_con, sbh8, mask, sighB, nullptr, out);
}